// Round 1
// baseline (383.983 us; speedup 1.0000x reference)
//
#include <hip/hip_runtime.h>

// GCN 2-layer forward for N=100000, D=128, E=600000.
// Pipeline per call:
//   memset(cnt,cursor) -> hist -> dinv -> scan(3 kernels) -> fill(CSR)
//   -> gemm1 -> agg1(+b1,relu) -> gemm2 -> agg2(+b2)

#define D 128

// ---------------- degree / CSR build ----------------

__global__ void k_hist(const int* __restrict__ dst, int E, int* __restrict__ cnt) {
    int i = blockIdx.x * blockDim.x + threadIdx.x;
    if (i < E) atomicAdd(&cnt[dst[i]], 1);
}

__global__ void k_dinv(const int* __restrict__ cnt, float* __restrict__ dinv, int n) {
    int i = blockIdx.x * blockDim.x + threadIdx.x;
    if (i < n) dinv[i] = rsqrtf((float)(cnt[i] + 1));  // +1 self-loop
}

// pass 1: per-block (1024 items) sums
__global__ void k_scan1(const int* __restrict__ cnt, int n, int* __restrict__ bsum) {
    __shared__ int lds[256];
    int t = threadIdx.x;
    int base = blockIdx.x * 1024 + t * 4;
    int s = 0;
#pragma unroll
    for (int j = 0; j < 4; ++j) {
        int i = base + j;
        if (i < n) s += cnt[i];
    }
    lds[t] = s;
    __syncthreads();
    for (int off = 128; off > 0; off >>= 1) {
        if (t < off) lds[t] += lds[t + off];
        __syncthreads();
    }
    if (t == 0) bsum[blockIdx.x] = lds[0];
}

// pass 2: tiny sequential exclusive scan of block sums (nb <= ~128)
__global__ void k_scan2(int* __restrict__ bsum, int nb, int* __restrict__ total) {
    if (threadIdx.x == 0 && blockIdx.x == 0) {
        int run = 0;
        for (int b = 0; b < nb; ++b) { int v = bsum[b]; bsum[b] = run; run += v; }
        *total = run;  // rowptr[N]
    }
}

// pass 3: block-local exclusive scan + block offset -> rowptr
__global__ void k_scan3(const int* __restrict__ cnt, int n,
                        const int* __restrict__ bsum, int* __restrict__ rowptr) {
    __shared__ int lds[256];
    int t = threadIdx.x;
    int base = blockIdx.x * 1024 + t * 4;
    int v0 = 0, v1 = 0, v2 = 0, v3 = 0;
    if (base + 0 < n) v0 = cnt[base + 0];
    if (base + 1 < n) v1 = cnt[base + 1];
    if (base + 2 < n) v2 = cnt[base + 2];
    if (base + 3 < n) v3 = cnt[base + 3];
    int s = v0 + v1 + v2 + v3;
    lds[t] = s;
    __syncthreads();
    int incl = s;
    for (int off = 1; off < 256; off <<= 1) {
        int add = (t >= off) ? lds[t - off] : 0;
        __syncthreads();
        incl += add;
        lds[t] = incl;
        __syncthreads();
    }
    int run = bsum[blockIdx.x] + (incl - s);  // exclusive prefix for this thread
    if (base + 0 < n) { rowptr[base + 0] = run; run += v0; }
    if (base + 1 < n) { rowptr[base + 1] = run; run += v1; }
    if (base + 2 < n) { rowptr[base + 2] = run; run += v2; }
    if (base + 3 < n) { rowptr[base + 3] = run; run += v3; }
}

__global__ void k_fill(const int* __restrict__ src, const int* __restrict__ dst, int E,
                       const int* __restrict__ rowptr, int* __restrict__ cursor,
                       int* __restrict__ col) {
    int i = blockIdx.x * blockDim.x + threadIdx.x;
    if (i < E) {
        int d = dst[i];
        int pos = rowptr[d] + atomicAdd(&cursor[d], 1);
        col[pos] = src[i];
    }
}

// ---------------- dense GEMM: H[n x 128] = X[n x 128] @ W[128 x 128] ----------------
// block = 256 threads, 128 rows/block; thread computes 4 rows x 16 cols.
__global__ __launch_bounds__(256) void k_gemm(const float* __restrict__ X,
                                              const float* __restrict__ W,
                                              float* __restrict__ H, int n) {
    __shared__ float sW[32 * 128];       // K-chunk of W: 32 x 128
    __shared__ float sX[128 * 33];       // row tile of X: 128 x 32 (+1 pad)
    const int tid = threadIdx.x;
    const int cg = tid & 7;              // col group: cols cg*16 .. +15
    const int rg = tid >> 3;             // row group: rows rg*4 .. +3
    const int rowBase = blockIdx.x * 128;

    float acc[4][16];
#pragma unroll
    for (int r = 0; r < 4; ++r)
#pragma unroll
        for (int c = 0; c < 16; ++c) acc[r][c] = 0.0f;

    for (int kt = 0; kt < 4; ++kt) {
        // load W chunk (rows kt*32..+31, all cols): 4096 floats = 1024 float4
#pragma unroll
        for (int j = 0; j < 4; ++j) {
            int fi = tid + j * 256;
            ((float4*)sW)[fi] = ((const float4*)(W + kt * 32 * D))[fi];
        }
        // load X tile: 128 rows x 32 k = 1024 float4
#pragma unroll
        for (int j = 0; j < 4; ++j) {
            int fi = tid + j * 256;
            int r = fi >> 3;             // 8 float4 per row
            int ko = (fi & 7) * 4;
            int grow = rowBase + r;
            float4 v = {0.f, 0.f, 0.f, 0.f};
            if (grow < n) v = ((const float4*)(X + (size_t)grow * D + kt * 32))[fi & 7];
            float* p = sX + r * 33 + ko;
            p[0] = v.x; p[1] = v.y; p[2] = v.z; p[3] = v.w;
        }
        __syncthreads();

#pragma unroll
        for (int kk = 0; kk < 32; ++kk) {
            const float* wrow = sW + kk * D + cg * 16;
            float4 w0 = *((const float4*)(wrow + 0));
            float4 w1 = *((const float4*)(wrow + 4));
            float4 w2 = *((const float4*)(wrow + 8));
            float4 w3 = *((const float4*)(wrow + 12));
            float xv[4];
#pragma unroll
            for (int r = 0; r < 4; ++r) xv[r] = sX[(rg * 4 + r) * 33 + kk];
#pragma unroll
            for (int r = 0; r < 4; ++r) {
                acc[r][0]  += xv[r] * w0.x; acc[r][1]  += xv[r] * w0.y;
                acc[r][2]  += xv[r] * w0.z; acc[r][3]  += xv[r] * w0.w;
                acc[r][4]  += xv[r] * w1.x; acc[r][5]  += xv[r] * w1.y;
                acc[r][6]  += xv[r] * w1.z; acc[r][7]  += xv[r] * w1.w;
                acc[r][8]  += xv[r] * w2.x; acc[r][9]  += xv[r] * w2.y;
                acc[r][10] += xv[r] * w2.z; acc[r][11] += xv[r] * w2.w;
                acc[r][12] += xv[r] * w3.x; acc[r][13] += xv[r] * w3.y;
                acc[r][14] += xv[r] * w3.z; acc[r][15] += xv[r] * w3.w;
            }
        }
        __syncthreads();
    }

#pragma unroll
    for (int r = 0; r < 4; ++r) {
        int grow = rowBase + rg * 4 + r;
        if (grow < n) {
#pragma unroll
            for (int j = 0; j < 4; ++j) {
                float4 o = {acc[r][j * 4 + 0], acc[r][j * 4 + 1],
                            acc[r][j * 4 + 2], acc[r][j * 4 + 3]};
                ((float4*)(H + (size_t)grow * D + cg * 16))[j] = o;
            }
        }
    }
}

// ---------------- aggregation: out[n] = sum_{e in in(n)} h[src]*dinv[src]*dinv[n]
//                              + h[n]*dinv[n]^2 + b   (optional relu) ----------------
// one wave (64 lanes) per node; lane covers d and d+64.
__global__ __launch_bounds__(256) void k_agg(const float* __restrict__ H,
                                             const int* __restrict__ rowptr,
                                             const int* __restrict__ col,
                                             const float* __restrict__ dinv,
                                             const float* __restrict__ bias,
                                             float* __restrict__ out, int n, int relu) {
    int wave = threadIdx.x >> 6;
    int lane = threadIdx.x & 63;
    int node = blockIdx.x * 4 + wave;
    if (node >= n) return;
    int beg = rowptr[node];
    int end = rowptr[node + 1];
    float dn = dinv[node];
    size_t nb = (size_t)node * D;
    float acc0 = H[nb + lane] * dn * dn;         // self-loop
    float acc1 = H[nb + 64 + lane] * dn * dn;
    for (int e = beg; e < end; ++e) {
        int s = col[e];
        float w = dinv[s] * dn;
        size_t sb = (size_t)s * D;
        acc0 += H[sb + lane] * w;
        acc1 += H[sb + 64 + lane] * w;
    }
    acc0 += bias[lane];
    acc1 += bias[64 + lane];
    if (relu) { acc0 = fmaxf(acc0, 0.0f); acc1 = fmaxf(acc1, 0.0f); }
    out[nb + lane] = acc0;
    out[nb + 64 + lane] = acc1;
}

// ---------------- launcher ----------------

extern "C" void kernel_launch(void* const* d_in, const int* in_sizes, int n_in,
                              void* d_out, int out_size, void* d_ws, size_t ws_size,
                              hipStream_t stream) {
    const float* x  = (const float*)d_in[0];
    const int*   ei = (const int*)d_in[1];
    const float* W1 = (const float*)d_in[2];
    const float* b1 = (const float*)d_in[3];
    const float* W2 = (const float*)d_in[4];
    const float* b2 = (const float*)d_in[5];
    float* out = (float*)d_out;

    const int N = in_sizes[0] / D;
    const int E = in_sizes[1] / 2;
    const int* srcv = ei;
    const int* dstv = ei + E;

    char* ws = (char*)d_ws;
    size_t off = 0;
    auto take = [&](size_t bytes) -> char* {
        char* p = ws + off;
        off += (bytes + 255) & ~(size_t)255;
        return p;
    };
    int*   cnt    = (int*)take((size_t)N * 4);
    int*   cursor = (int*)take((size_t)N * 4);
    float* dinv   = (float*)take((size_t)N * 4);
    int*   rowptr = (int*)take((size_t)(N + 1) * 4);
    int*   bsum   = (int*)take(4096);
    int*   colv   = (int*)take((size_t)E * 4);
    float* hA     = (float*)take((size_t)N * D * 4);
    float* hB     = (float*)take((size_t)N * D * 4);
    (void)ws_size; (void)n_in; (void)out_size;

    hipMemsetAsync(cnt, 0, (size_t)N * 4, stream);
    hipMemsetAsync(cursor, 0, (size_t)N * 4, stream);

    int nb = (N + 1023) / 1024;
    k_hist<<<(E + 255) / 256, 256, 0, stream>>>(dstv, E, cnt);
    k_dinv<<<(N + 255) / 256, 256, 0, stream>>>(cnt, dinv, N);
    k_scan1<<<nb, 256, 0, stream>>>(cnt, N, bsum);
    k_scan2<<<1, 64, 0, stream>>>(bsum, nb, rowptr + N);
    k_scan3<<<nb, 256, 0, stream>>>(cnt, N, bsum, rowptr);
    k_fill<<<(E + 255) / 256, 256, 0, stream>>>(srcv, dstv, E, rowptr, cursor, colv);

    int gemmBlocks = (N + 127) / 128;
    int aggBlocks  = (N + 3) / 4;
    k_gemm<<<gemmBlocks, 256, 0, stream>>>(x, W1, hA, N);
    k_agg<<<aggBlocks, 256, 0, stream>>>(hA, rowptr, colv, dinv, b1, hB, N, 1);
    k_gemm<<<gemmBlocks, 256, 0, stream>>>(hB, W2, hA, N);
    k_agg<<<aggBlocks, 256, 0, stream>>>(hA, rowptr, colv, dinv, b2, out, N, 0);
}

// Round 2
// 249.712 us; speedup vs baseline: 1.5377x; 1.5377x over previous
//
#include <hip/hip_runtime.h>

// GCN 2-layer forward, N=100000, D=128, E=600000.
// memset -> hist -> dinv -> scan(3) -> fill(CSR + per-edge {src,dinv[src]})
// -> wprep(x2) -> gemm1(MFMA bf16 3-product) -> agg1 -> gemm2 -> agg2

#define D 128

typedef __bf16 bf16x8 __attribute__((ext_vector_type(8)));
typedef float  f32x4  __attribute__((ext_vector_type(4)));

// ---------------- degree / CSR build ----------------

__global__ void k_hist(const int* __restrict__ dst, int E, int* __restrict__ cnt) {
    int i = blockIdx.x * blockDim.x + threadIdx.x;
    if (i < E) atomicAdd(&cnt[dst[i]], 1);
}

__global__ void k_dinv(const int* __restrict__ cnt, float* __restrict__ dinv, int n) {
    int i = blockIdx.x * blockDim.x + threadIdx.x;
    if (i < n) dinv[i] = rsqrtf((float)(cnt[i] + 1));  // +1 self-loop
}

__global__ void k_scan1(const int* __restrict__ cnt, int n, int* __restrict__ bsum) {
    __shared__ int lds[256];
    int t = threadIdx.x;
    int base = blockIdx.x * 1024 + t * 4;
    int s = 0;
#pragma unroll
    for (int j = 0; j < 4; ++j) {
        int i = base + j;
        if (i < n) s += cnt[i];
    }
    lds[t] = s;
    __syncthreads();
    for (int off = 128; off > 0; off >>= 1) {
        if (t < off) lds[t] += lds[t + off];
        __syncthreads();
    }
    if (t == 0) bsum[blockIdx.x] = lds[0];
}

// parallel exclusive scan of block sums (chunks of 128 with carry)
__global__ void k_scan2(int* __restrict__ bsum, int nb, int* __restrict__ total) {
    __shared__ int lds[128];
    __shared__ int carry;
    int t = threadIdx.x;
    if (t == 0) carry = 0;
    __syncthreads();
    for (int base = 0; base < nb; base += 128) {
        int v = (base + t < nb) ? bsum[base + t] : 0;
        lds[t] = v;
        __syncthreads();
        int incl = v;
        for (int off = 1; off < 128; off <<= 1) {
            int add = (t >= off) ? lds[t - off] : 0;
            __syncthreads();
            incl += add;
            lds[t] = incl;
            __syncthreads();
        }
        int c = carry;
        if (base + t < nb) bsum[base + t] = c + incl - v;
        __syncthreads();
        if (t == 127) carry = c + incl;
        __syncthreads();
    }
    if (t == 0) *total = carry;
}

__global__ void k_scan3(const int* __restrict__ cnt, int n,
                        const int* __restrict__ bsum, int* __restrict__ rowptr) {
    __shared__ int lds[256];
    int t = threadIdx.x;
    int base = blockIdx.x * 1024 + t * 4;
    int v0 = 0, v1 = 0, v2 = 0, v3 = 0;
    if (base + 0 < n) v0 = cnt[base + 0];
    if (base + 1 < n) v1 = cnt[base + 1];
    if (base + 2 < n) v2 = cnt[base + 2];
    if (base + 3 < n) v3 = cnt[base + 3];
    int s = v0 + v1 + v2 + v3;
    lds[t] = s;
    __syncthreads();
    int incl = s;
    for (int off = 1; off < 256; off <<= 1) {
        int add = (t >= off) ? lds[t - off] : 0;
        __syncthreads();
        incl += add;
        lds[t] = incl;
        __syncthreads();
    }
    int run = bsum[blockIdx.x] + (incl - s);
    if (base + 0 < n) { rowptr[base + 0] = run; run += v0; }
    if (base + 1 < n) { rowptr[base + 1] = run; run += v1; }
    if (base + 2 < n) { rowptr[base + 2] = run; run += v2; }
    if (base + 3 < n) { rowptr[base + 3] = run; run += v3; }
}

// CSR fill; edge record = {src, dinv[src] bits}
__global__ void k_fill(const int* __restrict__ src, const int* __restrict__ dst, int E,
                       const int* __restrict__ rowptr, int* __restrict__ cursor,
                       const float* __restrict__ dinv, int2* __restrict__ er) {
    int i = blockIdx.x * blockDim.x + threadIdx.x;
    if (i < E) {
        int d = dst[i];
        int s = src[i];
        int pos = rowptr[d] + atomicAdd(&cursor[d], 1);
        er[pos] = make_int2(s, __float_as_int(dinv[s]));
    }
}

// ---------------- W prep: fp32 -> bf16 hi/lo, packed in MFMA B-frag order ----------------
// frag element (kt, ni, lane, j) <- W[k][n], k = kt*32 + (lane>>4)*8 + j, n = ni*16 + (lane&15)
__global__ void k_wprep(const float* __restrict__ W,
                        __bf16* __restrict__ whi, __bf16* __restrict__ wlo) {
    int i = blockIdx.x * blockDim.x + threadIdx.x;
    if (i < D * D) {
        int k = i >> 7, n = i & 127;
        float w = W[i];
        __bf16 h = (__bf16)w;
        __bf16 l = (__bf16)(w - (float)h);
        int kt = k >> 5, kk = k & 31;
        int lane = (kk >> 3) * 16 + (n & 15);
        int off = (((kt * 8) + (n >> 4)) * 64 + lane) * 8 + (kk & 7);
        whi[off] = h;
        wlo[off] = l;
    }
}

// ---------------- MFMA GEMM: H[n x 128] = X[n x 128] @ W[128 x 128] ----------------
// 256 thr = 4 waves; wave owns 32 rows x 128 cols; 16x16x32 bf16 MFMA, 3-product hi/lo.
__device__ inline void cvt_hilo(float4 v0, float4 v1, bf16x8& hi, bf16x8& lo) {
    float x[8] = {v0.x, v0.y, v0.z, v0.w, v1.x, v1.y, v1.z, v1.w};
#pragma unroll
    for (int j = 0; j < 8; ++j) {
        __bf16 h = (__bf16)x[j];
        hi[j] = h;
        lo[j] = (__bf16)(x[j] - (float)h);
    }
}

__global__ __launch_bounds__(256) void k_gemm(const float* __restrict__ X,
                                              const __bf16* __restrict__ whi,
                                              const __bf16* __restrict__ wlo,
                                              float* __restrict__ H, int n) {
    const int tid = threadIdx.x;
    const int wid = tid >> 6;
    const int lane = tid & 63;
    const int lh = lane >> 4;   // k-group within frag
    const int lm = lane & 15;   // row within frag
    const int rowBase = blockIdx.x * 128 + wid * 32;

    // A fragments for all 4 k-steps, both 16-row groups, hi+lo
    bf16x8 ahi[2][4], alo[2][4];
#pragma unroll
    for (int mi = 0; mi < 2; ++mi) {
        int row = rowBase + mi * 16 + lm;
        if (row >= n) row = n - 1;  // clamp (stores are guarded)
        const float* xp = X + (size_t)row * D + lh * 8;
#pragma unroll
        for (int kt = 0; kt < 4; ++kt) {
            float4 v0 = ((const float4*)(xp + kt * 32))[0];
            float4 v1 = ((const float4*)(xp + kt * 32))[1];
            cvt_hilo(v0, v1, ahi[mi][kt], alo[mi][kt]);
        }
    }

    f32x4 acc[2][8];
#pragma unroll
    for (int mi = 0; mi < 2; ++mi)
#pragma unroll
        for (int ni = 0; ni < 8; ++ni) acc[mi][ni] = (f32x4){0.f, 0.f, 0.f, 0.f};

#pragma unroll
    for (int kt = 0; kt < 4; ++kt) {
#pragma unroll
        for (int ni = 0; ni < 8; ++ni) {
            int foff = ((kt * 8 + ni) * 64 + lane) * 8;
            bf16x8 bh = *(const bf16x8*)(whi + foff);
            bf16x8 bl = *(const bf16x8*)(wlo + foff);
#pragma unroll
            for (int mi = 0; mi < 2; ++mi) {
                acc[mi][ni] = __builtin_amdgcn_mfma_f32_16x16x32_bf16(ahi[mi][kt], bh, acc[mi][ni], 0, 0, 0);
                acc[mi][ni] = __builtin_amdgcn_mfma_f32_16x16x32_bf16(alo[mi][kt], bh, acc[mi][ni], 0, 0, 0);
                acc[mi][ni] = __builtin_amdgcn_mfma_f32_16x16x32_bf16(ahi[mi][kt], bl, acc[mi][ni], 0, 0, 0);
            }
        }
    }

    // C/D layout: col = lane&15, row = (lane>>4)*4 + r   [measured m89]
#pragma unroll
    for (int mi = 0; mi < 2; ++mi) {
        int r0 = rowBase + mi * 16 + (lane >> 4) * 4;
        int c = lane & 15;
#pragma unroll
        for (int ni = 0; ni < 8; ++ni) {
#pragma unroll
            for (int r = 0; r < 4; ++r) {
                int row = r0 + r;
                if (row < n) H[(size_t)row * D + ni * 16 + c] = acc[mi][ni][r];
            }
        }
    }
}

// ---------------- aggregation ----------------
// one wave per node; lane covers float2 at d = 2*lane; lane-parallel edge fetch,
// shfl broadcast, 8-deep predicated gather unroll.
__global__ __launch_bounds__(256) void k_agg(const float* __restrict__ H,
                                             const int* __restrict__ rowptr,
                                             const int2* __restrict__ er,
                                             const float* __restrict__ dinv,
                                             const float* __restrict__ bias,
                                             float* __restrict__ out, int n, int relu) {
    int wave = threadIdx.x >> 6;
    int lane = threadIdx.x & 63;
    int node = blockIdx.x * 4 + wave;
    if (node >= n) return;
    int beg = rowptr[node];
    int end = rowptr[node + 1];
    float dn = dinv[node];
    size_t nb = (size_t)node * D + lane * 2;
    float2 self = *(const float2*)(H + nb);
    float dn2 = dn * dn;
    float2 acc;
    acc.x = self.x * dn2;
    acc.y = self.y * dn2;

    for (int e0 = beg; e0 < end; e0 += 64) {
        int idx = e0 + lane;
        bool valid = idx < end;
        int s = 0;
        float w = 0.0f;
        if (valid) {
            int2 rec = er[idx];
            s = rec.x;
            w = __int_as_float(rec.y) * dn;
        }
        int cnt = end - e0;
        if (cnt > 64) cnt = 64;
        for (int j0 = 0; j0 < cnt; j0 += 8) {
#pragma unroll
            for (int u = 0; u < 8; ++u) {
                int j = j0 + u;
                int jc = j < 63 ? j : 63;
                int sj = __shfl(s, jc);
                float wj = __shfl(w, jc);
                if (j >= cnt) wj = 0.0f;
                float2 hv = *(const float2*)(H + (size_t)sj * D + lane * 2);
                acc.x += hv.x * wj;
                acc.y += hv.y * wj;
            }
        }
    }
    float2 bv = *(const float2*)(bias + lane * 2);
    acc.x += bv.x;
    acc.y += bv.y;
    if (relu) { acc.x = fmaxf(acc.x, 0.f); acc.y = fmaxf(acc.y, 0.f); }
    *(float2*)(out + nb) = acc;
}

// ---------------- launcher ----------------

extern "C" void kernel_launch(void* const* d_in, const int* in_sizes, int n_in,
                              void* d_out, int out_size, void* d_ws, size_t ws_size,
                              hipStream_t stream) {
    const float* x  = (const float*)d_in[0];
    const int*   ei = (const int*)d_in[1];
    const float* W1 = (const float*)d_in[2];
    const float* b1 = (const float*)d_in[3];
    const float* W2 = (const float*)d_in[4];
    const float* b2 = (const float*)d_in[5];
    float* out = (float*)d_out;

    const int N = in_sizes[0] / D;
    const int E = in_sizes[1] / 2;
    const int* srcv = ei;
    const int* dstv = ei + E;

    char* ws = (char*)d_ws;
    size_t off = 0;
    auto take = [&](size_t bytes) -> char* {
        char* p = ws + off;
        off += (bytes + 255) & ~(size_t)255;
        return p;
    };
    int*    cnt    = (int*)take((size_t)N * 4);
    int*    cursor = (int*)take((size_t)N * 4);
    float*  dinv   = (float*)take((size_t)N * 4);
    int*    rowptr = (int*)take((size_t)(N + 1) * 4);
    int*    bsum   = (int*)take(4096);
    int2*   er     = (int2*)take((size_t)E * 8);
    __bf16* whi1   = (__bf16*)take((size_t)D * D * 2);
    __bf16* wlo1   = (__bf16*)take((size_t)D * D * 2);
    __bf16* whi2   = (__bf16*)take((size_t)D * D * 2);
    __bf16* wlo2   = (__bf16*)take((size_t)D * D * 2);
    float*  hA     = (float*)take((size_t)N * D * 4);
    float*  hB     = (float*)take((size_t)N * D * 4);
    (void)ws_size; (void)n_in; (void)out_size;

    hipMemsetAsync(cnt, 0, (size_t)N * 4, stream);
    hipMemsetAsync(cursor, 0, (size_t)N * 4, stream);

    int nb = (N + 1023) / 1024;
    k_hist<<<(E + 255) / 256, 256, 0, stream>>>(dstv, E, cnt);
    k_dinv<<<(N + 255) / 256, 256, 0, stream>>>(cnt, dinv, N);
    k_scan1<<<nb, 256, 0, stream>>>(cnt, N, bsum);
    k_scan2<<<1, 128, 0, stream>>>(bsum, nb, rowptr + N);
    k_scan3<<<nb, 256, 0, stream>>>(cnt, N, bsum, rowptr);
    k_fill<<<(E + 255) / 256, 256, 0, stream>>>(srcv, dstv, E, rowptr, cursor, dinv, er);

    k_wprep<<<(D * D + 255) / 256, 256, 0, stream>>>(W1, whi1, wlo1);
    k_wprep<<<(D * D + 255) / 256, 256, 0, stream>>>(W2, whi2, wlo2);

    int gemmBlocks = (N + 127) / 128;
    int aggBlocks  = (N + 3) / 4;
    k_gemm<<<gemmBlocks, 256, 0, stream>>>(x, whi1, wlo1, hA, N);
    k_agg<<<aggBlocks, 256, 0, stream>>>(hA, rowptr, er, dinv, b1, hB, N, 1);
    k_gemm<<<gemmBlocks, 256, 0, stream>>>(hB, whi2, wlo2, hA, N);
    k_agg<<<aggBlocks, 256, 0, stream>>>(hA, rowptr, er, dinv, b2, out, N, 0);
}

// Round 3
// 196.004 us; speedup vs baseline: 1.9591x; 1.2740x over previous
//
#include <hip/hip_runtime.h>

// GCN 2-layer forward, N=100000, D=128, E=600000.
// memset(cnt) -> hist -> scan1+dinv -> scan3(self-scan bsum) -> fill(atomicSub)
// -> wprep(both) -> gemm1(f32 A, 3-prod, bf16 out) -> agg1(bf16->bf16,+b,relu)
// -> gemm2(bf16 A, 2-prod, bf16 out) -> agg2(bf16->f32,+b)

#define D 128

typedef __bf16 bf16x8 __attribute__((ext_vector_type(8)));
typedef float  f32x4  __attribute__((ext_vector_type(4)));

// ---------------- degree / CSR build ----------------

__global__ void k_hist(const int* __restrict__ dst, int E, int* __restrict__ cnt) {
    int i = blockIdx.x * blockDim.x + threadIdx.x;
    if (i < E) atomicAdd(&cnt[dst[i]], 1);
}

// per-1024-chunk sums + dinv fused
__global__ void k_scan1(const int* __restrict__ cnt, int n, int* __restrict__ bsum,
                        float* __restrict__ dinv) {
    __shared__ int lds[256];
    int t = threadIdx.x;
    int base = blockIdx.x * 1024 + t * 4;
    int s = 0;
#pragma unroll
    for (int j = 0; j < 4; ++j) {
        int i = base + j;
        if (i < n) {
            int c = cnt[i];
            s += c;
            dinv[i] = rsqrtf((float)(c + 1));  // +1 self-loop
        }
    }
    lds[t] = s;
    __syncthreads();
    for (int off = 128; off > 0; off >>= 1) {
        if (t < off) lds[t] += lds[t + off];
        __syncthreads();
    }
    if (t == 0) bsum[blockIdx.x] = lds[0];
}

// block-local exclusive scan + self-computed block offset (reduces bsum[0..blk))
__global__ void k_scan3(const int* __restrict__ cnt, int n, int nb,
                        const int* __restrict__ bsum, int* __restrict__ rowptr, int E) {
    __shared__ int lds[256];
    __shared__ int blockOff;
    int t = threadIdx.x;
    // exclusive prefix over chunk sums
    lds[t] = (t < nb && t < (int)blockIdx.x) ? bsum[t] : 0;
    __syncthreads();
    for (int off = 128; off > 0; off >>= 1) {
        if (t < off) lds[t] += lds[t + off];
        __syncthreads();
    }
    if (t == 0) blockOff = lds[0];
    __syncthreads();

    int base = blockIdx.x * 1024 + t * 4;
    int v0 = 0, v1 = 0, v2 = 0, v3 = 0;
    if (base + 0 < n) v0 = cnt[base + 0];
    if (base + 1 < n) v1 = cnt[base + 1];
    if (base + 2 < n) v2 = cnt[base + 2];
    if (base + 3 < n) v3 = cnt[base + 3];
    int s = v0 + v1 + v2 + v3;
    lds[t] = s;
    __syncthreads();
    int incl = s;
    for (int off = 1; off < 256; off <<= 1) {
        int add = (t >= off) ? lds[t - off] : 0;
        __syncthreads();
        incl += add;
        lds[t] = incl;
        __syncthreads();
    }
    int run = blockOff + (incl - s);
    if (base + 0 < n) { rowptr[base + 0] = run; run += v0; }
    if (base + 1 < n) { rowptr[base + 1] = run; run += v1; }
    if (base + 2 < n) { rowptr[base + 2] = run; run += v2; }
    if (base + 3 < n) { rowptr[base + 3] = run; run += v3; }
    if (blockIdx.x == 0 && t == 0) rowptr[n] = E;  // total = E exactly
}

// CSR fill; consumes cnt (atomicSub) so no cursor buffer; edge rec = {src, dinv[src]}
__global__ void k_fill(const int* __restrict__ src, const int* __restrict__ dst, int E,
                       const int* __restrict__ rowptr, int* __restrict__ cnt,
                       const float* __restrict__ dinv, int2* __restrict__ er) {
    int i = blockIdx.x * blockDim.x + threadIdx.x;
    if (i < E) {
        int d = dst[i];
        int s = src[i];
        int pos = rowptr[d] + atomicSub(&cnt[d], 1) - 1;
        er[pos] = make_int2(s, __float_as_int(dinv[s]));
    }
}

// ---------------- W prep: fp32 -> bf16 hi/lo, packed in MFMA B-frag order ----------------
// frag element (kt, ni, lane, j) <- W[k][n], k = kt*32 + (lane>>4)*8 + j, n = ni*16 + (lane&15)
__global__ void k_wprep(const float* __restrict__ W1, const float* __restrict__ W2,
                        __bf16* __restrict__ whi1, __bf16* __restrict__ wlo1,
                        __bf16* __restrict__ whi2, __bf16* __restrict__ wlo2) {
    int i = blockIdx.x * blockDim.x + threadIdx.x;
    if (i >= 2 * D * D) return;
    const float* W = (i < D * D) ? W1 : W2;
    __bf16* whi = (i < D * D) ? whi1 : whi2;
    __bf16* wlo = (i < D * D) ? wlo1 : wlo2;
    int ii = i & (D * D - 1);
    int k = ii >> 7, n = ii & 127;
    float w = W[ii];
    __bf16 h = (__bf16)w;
    __bf16 l = (__bf16)(w - (float)h);
    int kt = k >> 5, kk = k & 31;
    int lane = (kk >> 3) * 16 + (n & 15);
    int off = (((kt * 8) + (n >> 4)) * 64 + lane) * 8 + (kk & 7);
    whi[off] = h;
    wlo[off] = l;
}

// ---------------- MFMA GEMMs: H[n x 128] = A[n x 128] @ W[128 x 128] ----------------

__device__ inline void cvt_hilo(float4 v0, float4 v1, bf16x8& hi, bf16x8& lo) {
    float x[8] = {v0.x, v0.y, v0.z, v0.w, v1.x, v1.y, v1.z, v1.w};
#pragma unroll
    for (int j = 0; j < 8; ++j) {
        __bf16 h = (__bf16)x[j];
        hi[j] = h;
        lo[j] = (__bf16)(x[j] - (float)h);
    }
}

// layer 1: fp32 A, 3-product, bf16 output
__global__ __launch_bounds__(256) void k_gemm1(const float* __restrict__ X,
                                               const __bf16* __restrict__ whi,
                                               const __bf16* __restrict__ wlo,
                                               __bf16* __restrict__ H, int n) {
    const int tid = threadIdx.x;
    const int wid = tid >> 6;
    const int lane = tid & 63;
    const int lh = lane >> 4;
    const int lm = lane & 15;
    const int rowBase = blockIdx.x * 128 + wid * 32;

    bf16x8 ahi[2][4], alo[2][4];
#pragma unroll
    for (int mi = 0; mi < 2; ++mi) {
        int row = rowBase + mi * 16 + lm;
        if (row >= n) row = n - 1;
        const float* xp = X + (size_t)row * D + lh * 8;
#pragma unroll
        for (int kt = 0; kt < 4; ++kt) {
            float4 v0 = ((const float4*)(xp + kt * 32))[0];
            float4 v1 = ((const float4*)(xp + kt * 32))[1];
            cvt_hilo(v0, v1, ahi[mi][kt], alo[mi][kt]);
        }
    }

    f32x4 acc[2][8];
#pragma unroll
    for (int mi = 0; mi < 2; ++mi)
#pragma unroll
        for (int ni = 0; ni < 8; ++ni) acc[mi][ni] = (f32x4){0.f, 0.f, 0.f, 0.f};

#pragma unroll
    for (int kt = 0; kt < 4; ++kt) {
#pragma unroll
        for (int ni = 0; ni < 8; ++ni) {
            int foff = ((kt * 8 + ni) * 64 + lane) * 8;
            bf16x8 bh = *(const bf16x8*)(whi + foff);
            bf16x8 bl = *(const bf16x8*)(wlo + foff);
#pragma unroll
            for (int mi = 0; mi < 2; ++mi) {
                acc[mi][ni] = __builtin_amdgcn_mfma_f32_16x16x32_bf16(ahi[mi][kt], bh, acc[mi][ni], 0, 0, 0);
                acc[mi][ni] = __builtin_amdgcn_mfma_f32_16x16x32_bf16(alo[mi][kt], bh, acc[mi][ni], 0, 0, 0);
                acc[mi][ni] = __builtin_amdgcn_mfma_f32_16x16x32_bf16(ahi[mi][kt], bl, acc[mi][ni], 0, 0, 0);
            }
        }
    }

#pragma unroll
    for (int mi = 0; mi < 2; ++mi) {
        int r0 = rowBase + mi * 16 + (lane >> 4) * 4;
        int c = lane & 15;
#pragma unroll
        for (int ni = 0; ni < 8; ++ni) {
#pragma unroll
            for (int r = 0; r < 4; ++r) {
                int row = r0 + r;
                if (row < n) H[(size_t)row * D + ni * 16 + c] = (__bf16)acc[mi][ni][r];
            }
        }
    }
}

// layer 2: bf16 A (exact), 2-product, bf16 output
__global__ __launch_bounds__(256) void k_gemm2(const __bf16* __restrict__ X,
                                               const __bf16* __restrict__ whi,
                                               const __bf16* __restrict__ wlo,
                                               __bf16* __restrict__ H, int n) {
    const int tid = threadIdx.x;
    const int wid = tid >> 6;
    const int lane = tid & 63;
    const int lh = lane >> 4;
    const int lm = lane & 15;
    const int rowBase = blockIdx.x * 128 + wid * 32;

    bf16x8 a[2][4];
#pragma unroll
    for (int mi = 0; mi < 2; ++mi) {
        int row = rowBase + mi * 16 + lm;
        if (row >= n) row = n - 1;
        const __bf16* xp = X + (size_t)row * D + lh * 8;
#pragma unroll
        for (int kt = 0; kt < 4; ++kt) a[mi][kt] = *(const bf16x8*)(xp + kt * 32);
    }

    f32x4 acc[2][8];
#pragma unroll
    for (int mi = 0; mi < 2; ++mi)
#pragma unroll
        for (int ni = 0; ni < 8; ++ni) acc[mi][ni] = (f32x4){0.f, 0.f, 0.f, 0.f};

#pragma unroll
    for (int kt = 0; kt < 4; ++kt) {
#pragma unroll
        for (int ni = 0; ni < 8; ++ni) {
            int foff = ((kt * 8 + ni) * 64 + lane) * 8;
            bf16x8 bh = *(const bf16x8*)(whi + foff);
            bf16x8 bl = *(const bf16x8*)(wlo + foff);
#pragma unroll
            for (int mi = 0; mi < 2; ++mi) {
                acc[mi][ni] = __builtin_amdgcn_mfma_f32_16x16x32_bf16(a[mi][kt], bh, acc[mi][ni], 0, 0, 0);
                acc[mi][ni] = __builtin_amdgcn_mfma_f32_16x16x32_bf16(a[mi][kt], bl, acc[mi][ni], 0, 0, 0);
            }
        }
    }

#pragma unroll
    for (int mi = 0; mi < 2; ++mi) {
        int r0 = rowBase + mi * 16 + (lane >> 4) * 4;
        int c = lane & 15;
#pragma unroll
        for (int ni = 0; ni < 8; ++ni) {
#pragma unroll
            for (int r = 0; r < 4; ++r) {
                int row = r0 + r;
                if (row < n) H[(size_t)row * D + ni * 16 + c] = (__bf16)acc[mi][ni][r];
            }
        }
    }
}

// ---------------- aggregation (bf16 H gather) ----------------
// one wave per node; lane covers bf16x2 at d = 2*lane (4 B per lane).

__device__ inline void bf2_unpack(unsigned v, float& a, float& b) {
    a = __uint_as_float(v << 16);
    b = __uint_as_float(v & 0xffff0000u);
}

template <int RELU, int OUTBF>
__global__ __launch_bounds__(256) void k_agg(const __bf16* __restrict__ H,
                                             const int* __restrict__ rowptr,
                                             const int2* __restrict__ er,
                                             const float* __restrict__ dinv,
                                             const float* __restrict__ bias,
                                             __bf16* __restrict__ outb,
                                             float* __restrict__ outf, int n) {
    int wave = threadIdx.x >> 6;
    int lane = threadIdx.x & 63;
    int node = blockIdx.x * 4 + wave;
    if (node >= n) return;
    int beg = rowptr[node];
    int end = rowptr[node + 1];
    float dn = dinv[node];
    size_t nb = (size_t)node * D + lane * 2;
    float s0, s1;
    bf2_unpack(*(const unsigned*)(H + nb), s0, s1);
    float dn2 = dn * dn;
    float accx = s0 * dn2, accy = s1 * dn2;

    for (int e0 = beg; e0 < end; e0 += 64) {
        int idx = e0 + lane;
        int s = 0;
        float w = 0.0f;
        if (idx < end) {
            int2 rec = er[idx];
            s = rec.x;
            w = __int_as_float(rec.y) * dn;
        }
        int cnt = end - e0;
        if (cnt > 64) cnt = 64;
        for (int j0 = 0; j0 < cnt; j0 += 8) {
#pragma unroll
            for (int u = 0; u < 8; ++u) {
                int j = j0 + u;
                int jc = j < 63 ? j : 63;
                int sj = __shfl(s, jc);
                float wj = __shfl(w, jc);
                if (j >= cnt) wj = 0.0f;
                unsigned hv = *(const unsigned*)(H + (size_t)sj * D + lane * 2);
                float h0, h1;
                bf2_unpack(hv, h0, h1);
                accx += h0 * wj;
                accy += h1 * wj;
            }
        }
    }
    float2 bv = *(const float2*)(bias + lane * 2);
    accx += bv.x;
    accy += bv.y;
    if (RELU) { accx = fmaxf(accx, 0.f); accy = fmaxf(accy, 0.f); }
    if (OUTBF) {
        __bf16 p0 = (__bf16)accx, p1 = (__bf16)accy;
        unsigned pk = ((unsigned)*(unsigned short*)&p1 << 16) | *(unsigned short*)&p0;
        *(unsigned*)(outb + nb) = pk;
    } else {
        *(float2*)(outf + nb) = make_float2(accx, accy);
    }
}

// ---------------- launcher ----------------

extern "C" void kernel_launch(void* const* d_in, const int* in_sizes, int n_in,
                              void* d_out, int out_size, void* d_ws, size_t ws_size,
                              hipStream_t stream) {
    const float* x  = (const float*)d_in[0];
    const int*   ei = (const int*)d_in[1];
    const float* W1 = (const float*)d_in[2];
    const float* b1 = (const float*)d_in[3];
    const float* W2 = (const float*)d_in[4];
    const float* b2 = (const float*)d_in[5];
    float* out = (float*)d_out;

    const int N = in_sizes[0] / D;
    const int E = in_sizes[1] / 2;
    const int* srcv = ei;
    const int* dstv = ei + E;

    char* ws = (char*)d_ws;
    size_t off = 0;
    auto take = [&](size_t bytes) -> char* {
        char* p = ws + off;
        off += (bytes + 255) & ~(size_t)255;
        return p;
    };
    int*    cnt    = (int*)take((size_t)N * 4);
    float*  dinv   = (float*)take((size_t)N * 4);
    int*    rowptr = (int*)take((size_t)(N + 1) * 4);
    int*    bsum   = (int*)take(4096);
    int2*   er     = (int2*)take((size_t)E * 8);
    __bf16* whi1   = (__bf16*)take((size_t)D * D * 2);
    __bf16* wlo1   = (__bf16*)take((size_t)D * D * 2);
    __bf16* whi2   = (__bf16*)take((size_t)D * D * 2);
    __bf16* wlo2   = (__bf16*)take((size_t)D * D * 2);
    __bf16* hA     = (__bf16*)take((size_t)N * D * 2);
    __bf16* hB     = (__bf16*)take((size_t)N * D * 2);
    (void)ws_size; (void)n_in; (void)out_size;

    hipMemsetAsync(cnt, 0, (size_t)N * 4, stream);

    int nb = (N + 1023) / 1024;
    k_hist<<<(E + 255) / 256, 256, 0, stream>>>(dstv, E, cnt);
    k_scan1<<<nb, 256, 0, stream>>>(cnt, N, bsum, dinv);
    k_scan3<<<nb, 256, 0, stream>>>(cnt, N, nb, bsum, rowptr, E);
    k_fill<<<(E + 255) / 256, 256, 0, stream>>>(srcv, dstv, E, rowptr, cnt, dinv, er);
    k_wprep<<<(2 * D * D + 255) / 256, 256, 0, stream>>>(W1, W2, whi1, wlo1, whi2, wlo2);

    int gemmBlocks = (N + 127) / 128;
    int aggBlocks  = (N + 3) / 4;
    k_gemm1<<<gemmBlocks, 256, 0, stream>>>(x, whi1, wlo1, hA, N);
    k_agg<1, 1><<<aggBlocks, 256, 0, stream>>>(hA, rowptr, er, dinv, b1, hB, nullptr, N);
    k_gemm2<<<gemmBlocks, 256, 0, stream>>>(hB, whi2, wlo2, hA, N);
    k_agg<0, 0><<<aggBlocks, 256, 0, stream>>>(hA, rowptr, er, dinv, b2, nullptr, out, N);
}

// Round 4
// 194.071 us; speedup vs baseline: 1.9786x; 1.0100x over previous
//
#include <hip/hip_runtime.h>

// GCN 2-layer forward, N=100000, D=128, E=600000.
// zero+wprep -> hist -> scan1+dinv -> scan3(self-scan bsum) -> fill(atomicSub)
// -> gemm1(f32 A, 3-prod, bf16 out) -> agg1(bf16->bf16,+b,relu)
// -> gemm2(bf16 A, 2-prod, bf16 out) -> agg2(bf16->f32,+b)
// NOTE: no hipMemsetAsync — the captured rocclr fill kernel costs ~39us/replay.

#define D 128

typedef __bf16 bf16x8 __attribute__((ext_vector_type(8)));
typedef float  f32x4  __attribute__((ext_vector_type(4)));

// ---------------- zero cnt + W prep (fused, independent ranges) ----------------
// wprep: fp32 -> bf16 hi/lo, packed in MFMA B-frag order
// frag element (kt, ni, lane, j) <- W[k][n], k = kt*32 + (lane>>4)*8 + j, n = ni*16 + (lane&15)
__global__ void k_zero_wprep(int* __restrict__ cnt, int n,
                             const float* __restrict__ W1, const float* __restrict__ W2,
                             __bf16* __restrict__ whi1, __bf16* __restrict__ wlo1,
                             __bf16* __restrict__ whi2, __bf16* __restrict__ wlo2) {
    int i = blockIdx.x * blockDim.x + threadIdx.x;
    if (i < n) cnt[i] = 0;
    if (i < 2 * D * D) {
        const float* W = (i < D * D) ? W1 : W2;
        __bf16* whi = (i < D * D) ? whi1 : whi2;
        __bf16* wlo = (i < D * D) ? wlo1 : wlo2;
        int ii = i & (D * D - 1);
        int k = ii >> 7, nn = ii & 127;
        float w = W[ii];
        __bf16 h = (__bf16)w;
        __bf16 l = (__bf16)(w - (float)h);
        int kt = k >> 5, kk = k & 31;
        int lane = (kk >> 3) * 16 + (nn & 15);
        int off = (((kt * 8) + (nn >> 4)) * 64 + lane) * 8 + (kk & 7);
        whi[off] = h;
        wlo[off] = l;
    }
}

// ---------------- degree / CSR build ----------------

__global__ void k_hist(const int* __restrict__ dst, int E, int* __restrict__ cnt) {
    int i = blockIdx.x * blockDim.x + threadIdx.x;
    if (i < E) atomicAdd(&cnt[dst[i]], 1);
}

// per-1024-chunk sums + dinv fused
__global__ void k_scan1(const int* __restrict__ cnt, int n, int* __restrict__ bsum,
                        float* __restrict__ dinv) {
    __shared__ int lds[256];
    int t = threadIdx.x;
    int base = blockIdx.x * 1024 + t * 4;
    int s = 0;
#pragma unroll
    for (int j = 0; j < 4; ++j) {
        int i = base + j;
        if (i < n) {
            int c = cnt[i];
            s += c;
            dinv[i] = rsqrtf((float)(c + 1));  // +1 self-loop
        }
    }
    lds[t] = s;
    __syncthreads();
    for (int off = 128; off > 0; off >>= 1) {
        if (t < off) lds[t] += lds[t + off];
        __syncthreads();
    }
    if (t == 0) bsum[blockIdx.x] = lds[0];
}

// block-local exclusive scan + self-computed block offset (reduces bsum[0..blk))
__global__ void k_scan3(const int* __restrict__ cnt, int n, int nb,
                        const int* __restrict__ bsum, int* __restrict__ rowptr, int E) {
    __shared__ int lds[256];
    __shared__ int blockOff;
    int t = threadIdx.x;
    lds[t] = (t < nb && t < (int)blockIdx.x) ? bsum[t] : 0;
    __syncthreads();
    for (int off = 128; off > 0; off >>= 1) {
        if (t < off) lds[t] += lds[t + off];
        __syncthreads();
    }
    if (t == 0) blockOff = lds[0];
    __syncthreads();

    int base = blockIdx.x * 1024 + t * 4;
    int v0 = 0, v1 = 0, v2 = 0, v3 = 0;
    if (base + 0 < n) v0 = cnt[base + 0];
    if (base + 1 < n) v1 = cnt[base + 1];
    if (base + 2 < n) v2 = cnt[base + 2];
    if (base + 3 < n) v3 = cnt[base + 3];
    int s = v0 + v1 + v2 + v3;
    lds[t] = s;
    __syncthreads();
    int incl = s;
    for (int off = 1; off < 256; off <<= 1) {
        int add = (t >= off) ? lds[t - off] : 0;
        __syncthreads();
        incl += add;
        lds[t] = incl;
        __syncthreads();
    }
    int run = blockOff + (incl - s);
    if (base + 0 < n) { rowptr[base + 0] = run; run += v0; }
    if (base + 1 < n) { rowptr[base + 1] = run; run += v1; }
    if (base + 2 < n) { rowptr[base + 2] = run; run += v2; }
    if (base + 3 < n) { rowptr[base + 3] = run; run += v3; }
    if (blockIdx.x == 0 && t == 0) rowptr[n] = E;  // total = E exactly
}

// CSR fill; consumes cnt (atomicSub) so no cursor buffer; edge rec = {src, dinv[src]}
__global__ void k_fill(const int* __restrict__ src, const int* __restrict__ dst, int E,
                       const int* __restrict__ rowptr, int* __restrict__ cnt,
                       const float* __restrict__ dinv, int2* __restrict__ er) {
    int i = blockIdx.x * blockDim.x + threadIdx.x;
    if (i < E) {
        int d = dst[i];
        int s = src[i];
        int pos = rowptr[d] + atomicSub(&cnt[d], 1) - 1;
        er[pos] = make_int2(s, __float_as_int(dinv[s]));
    }
}

// ---------------- MFMA GEMMs: H[n x 128] = A[n x 128] @ W[128 x 128] ----------------

__device__ inline void cvt_hilo(float4 v0, float4 v1, bf16x8& hi, bf16x8& lo) {
    float x[8] = {v0.x, v0.y, v0.z, v0.w, v1.x, v1.y, v1.z, v1.w};
#pragma unroll
    for (int j = 0; j < 8; ++j) {
        __bf16 h = (__bf16)x[j];
        hi[j] = h;
        lo[j] = (__bf16)(x[j] - (float)h);
    }
}

// layer 1: fp32 A, 3-product, bf16 output
__global__ __launch_bounds__(256) void k_gemm1(const float* __restrict__ X,
                                               const __bf16* __restrict__ whi,
                                               const __bf16* __restrict__ wlo,
                                               __bf16* __restrict__ H, int n) {
    const int tid = threadIdx.x;
    const int wid = tid >> 6;
    const int lane = tid & 63;
    const int lh = lane >> 4;
    const int lm = lane & 15;
    const int rowBase = blockIdx.x * 128 + wid * 32;

    bf16x8 ahi[2][4], alo[2][4];
#pragma unroll
    for (int mi = 0; mi < 2; ++mi) {
        int row = rowBase + mi * 16 + lm;
        if (row >= n) row = n - 1;
        const float* xp = X + (size_t)row * D + lh * 8;
#pragma unroll
        for (int kt = 0; kt < 4; ++kt) {
            float4 v0 = ((const float4*)(xp + kt * 32))[0];
            float4 v1 = ((const float4*)(xp + kt * 32))[1];
            cvt_hilo(v0, v1, ahi[mi][kt], alo[mi][kt]);
        }
    }

    f32x4 acc[2][8];
#pragma unroll
    for (int mi = 0; mi < 2; ++mi)
#pragma unroll
        for (int ni = 0; ni < 8; ++ni) acc[mi][ni] = (f32x4){0.f, 0.f, 0.f, 0.f};

#pragma unroll
    for (int kt = 0; kt < 4; ++kt) {
#pragma unroll
        for (int ni = 0; ni < 8; ++ni) {
            int foff = ((kt * 8 + ni) * 64 + lane) * 8;
            bf16x8 bh = *(const bf16x8*)(whi + foff);
            bf16x8 bl = *(const bf16x8*)(wlo + foff);
#pragma unroll
            for (int mi = 0; mi < 2; ++mi) {
                acc[mi][ni] = __builtin_amdgcn_mfma_f32_16x16x32_bf16(ahi[mi][kt], bh, acc[mi][ni], 0, 0, 0);
                acc[mi][ni] = __builtin_amdgcn_mfma_f32_16x16x32_bf16(alo[mi][kt], bh, acc[mi][ni], 0, 0, 0);
                acc[mi][ni] = __builtin_amdgcn_mfma_f32_16x16x32_bf16(ahi[mi][kt], bl, acc[mi][ni], 0, 0, 0);
            }
        }
    }

#pragma unroll
    for (int mi = 0; mi < 2; ++mi) {
        int r0 = rowBase + mi * 16 + (lane >> 4) * 4;
        int c = lane & 15;
#pragma unroll
        for (int ni = 0; ni < 8; ++ni) {
#pragma unroll
            for (int r = 0; r < 4; ++r) {
                int row = r0 + r;
                if (row < n) H[(size_t)row * D + ni * 16 + c] = (__bf16)acc[mi][ni][r];
            }
        }
    }
}

// layer 2: bf16 A (exact), 2-product, bf16 output
__global__ __launch_bounds__(256) void k_gemm2(const __bf16* __restrict__ X,
                                               const __bf16* __restrict__ whi,
                                               const __bf16* __restrict__ wlo,
                                               __bf16* __restrict__ H, int n) {
    const int tid = threadIdx.x;
    const int wid = tid >> 6;
    const int lane = tid & 63;
    const int lh = lane >> 4;
    const int lm = lane & 15;
    const int rowBase = blockIdx.x * 128 + wid * 32;

    bf16x8 a[2][4];
#pragma unroll
    for (int mi = 0; mi < 2; ++mi) {
        int row = rowBase + mi * 16 + lm;
        if (row >= n) row = n - 1;
        const __bf16* xp = X + (size_t)row * D + lh * 8;
#pragma unroll
        for (int kt = 0; kt < 4; ++kt) a[mi][kt] = *(const bf16x8*)(xp + kt * 32);
    }

    f32x4 acc[2][8];
#pragma unroll
    for (int mi = 0; mi < 2; ++mi)
#pragma unroll
        for (int ni = 0; ni < 8; ++ni) acc[mi][ni] = (f32x4){0.f, 0.f, 0.f, 0.f};

#pragma unroll
    for (int kt = 0; kt < 4; ++kt) {
#pragma unroll
        for (int ni = 0; ni < 8; ++ni) {
            int foff = ((kt * 8 + ni) * 64 + lane) * 8;
            bf16x8 bh = *(const bf16x8*)(whi + foff);
            bf16x8 bl = *(const bf16x8*)(wlo + foff);
#pragma unroll
            for (int mi = 0; mi < 2; ++mi) {
                acc[mi][ni] = __builtin_amdgcn_mfma_f32_16x16x32_bf16(a[mi][kt], bh, acc[mi][ni], 0, 0, 0);
                acc[mi][ni] = __builtin_amdgcn_mfma_f32_16x16x32_bf16(a[mi][kt], bl, acc[mi][ni], 0, 0, 0);
            }
        }
    }

#pragma unroll
    for (int mi = 0; mi < 2; ++mi) {
        int r0 = rowBase + mi * 16 + (lane >> 4) * 4;
        int c = lane & 15;
#pragma unroll
        for (int ni = 0; ni < 8; ++ni) {
#pragma unroll
            for (int r = 0; r < 4; ++r) {
                int row = r0 + r;
                if (row < n) H[(size_t)row * D + ni * 16 + c] = (__bf16)acc[mi][ni][r];
            }
        }
    }
}

// ---------------- aggregation (bf16 H gather) ----------------
// one wave per node; lane covers bf16x2 at d = 2*lane (4 B per lane).

__device__ inline void bf2_unpack(unsigned v, float& a, float& b) {
    a = __uint_as_float(v << 16);
    b = __uint_as_float(v & 0xffff0000u);
}

template <int RELU, int OUTBF>
__global__ __launch_bounds__(256) void k_agg(const __bf16* __restrict__ H,
                                             const int* __restrict__ rowptr,
                                             const int2* __restrict__ er,
                                             const float* __restrict__ dinv,
                                             const float* __restrict__ bias,
                                             __bf16* __restrict__ outb,
                                             float* __restrict__ outf, int n) {
    int wave = threadIdx.x >> 6;
    int lane = threadIdx.x & 63;
    int node = blockIdx.x * 4 + wave;
    if (node >= n) return;
    int beg = rowptr[node];
    int end = rowptr[node + 1];
    float dn = dinv[node];
    size_t nb = (size_t)node * D + lane * 2;
    float s0, s1;
    bf2_unpack(*(const unsigned*)(H + nb), s0, s1);
    float dn2 = dn * dn;
    float accx = s0 * dn2, accy = s1 * dn2;

    for (int e0 = beg; e0 < end; e0 += 64) {
        int idx = e0 + lane;
        int s = 0;
        float w = 0.0f;
        if (idx < end) {
            int2 rec = er[idx];
            s = rec.x;
            w = __int_as_float(rec.y) * dn;
        }
        int cnt = end - e0;
        if (cnt > 64) cnt = 64;
        for (int j0 = 0; j0 < cnt; j0 += 8) {
#pragma unroll
            for (int u = 0; u < 8; ++u) {
                int j = j0 + u;
                int jc = j < 63 ? j : 63;
                int sj = __shfl(s, jc);
                float wj = __shfl(w, jc);
                if (j >= cnt) wj = 0.0f;
                unsigned hv = *(const unsigned*)(H + (size_t)sj * D + lane * 2);
                float h0, h1;
                bf2_unpack(hv, h0, h1);
                accx += h0 * wj;
                accy += h1 * wj;
            }
        }
    }
    float2 bv = *(const float2*)(bias + lane * 2);
    accx += bv.x;
    accy += bv.y;
    if (RELU) { accx = fmaxf(accx, 0.f); accy = fmaxf(accy, 0.f); }
    if (OUTBF) {
        __bf16 p0 = (__bf16)accx, p1 = (__bf16)accy;
        unsigned pk = ((unsigned)*(unsigned short*)&p1 << 16) | *(unsigned short*)&p0;
        *(unsigned*)(outb + nb) = pk;
    } else {
        *(float2*)(outf + nb) = make_float2(accx, accy);
    }
}

// ---------------- launcher ----------------

extern "C" void kernel_launch(void* const* d_in, const int* in_sizes, int n_in,
                              void* d_out, int out_size, void* d_ws, size_t ws_size,
                              hipStream_t stream) {
    const float* x  = (const float*)d_in[0];
    const int*   ei = (const int*)d_in[1];
    const float* W1 = (const float*)d_in[2];
    const float* b1 = (const float*)d_in[3];
    const float* W2 = (const float*)d_in[4];
    const float* b2 = (const float*)d_in[5];
    float* out = (float*)d_out;

    const int N = in_sizes[0] / D;
    const int E = in_sizes[1] / 2;
    const int* srcv = ei;
    const int* dstv = ei + E;

    char* ws = (char*)d_ws;
    size_t off = 0;
    auto take = [&](size_t bytes) -> char* {
        char* p = ws + off;
        off += (bytes + 255) & ~(size_t)255;
        return p;
    };
    int*    cnt    = (int*)take((size_t)N * 4);
    float*  dinv   = (float*)take((size_t)N * 4);
    int*    rowptr = (int*)take((size_t)(N + 1) * 4);
    int*    bsum   = (int*)take(4096);
    int2*   er     = (int2*)take((size_t)E * 8);
    __bf16* whi1   = (__bf16*)take((size_t)D * D * 2);
    __bf16* wlo1   = (__bf16*)take((size_t)D * D * 2);
    __bf16* whi2   = (__bf16*)take((size_t)D * D * 2);
    __bf16* wlo2   = (__bf16*)take((size_t)D * D * 2);
    __bf16* hA     = (__bf16*)take((size_t)N * D * 2);
    __bf16* hB     = (__bf16*)take((size_t)N * D * 2);
    (void)ws_size; (void)n_in; (void)out_size;

    int nb = (N + 1023) / 1024;
    int zwBlocks = (N > 2 * D * D ? N : 2 * D * D);
    k_zero_wprep<<<(zwBlocks + 255) / 256, 256, 0, stream>>>(cnt, N, W1, W2,
                                                             whi1, wlo1, whi2, wlo2);
    k_hist<<<(E + 255) / 256, 256, 0, stream>>>(dstv, E, cnt);
    k_scan1<<<nb, 256, 0, stream>>>(cnt, N, bsum, dinv);
    k_scan3<<<nb, 256, 0, stream>>>(cnt, N, nb, bsum, rowptr, E);
    k_fill<<<(E + 255) / 256, 256, 0, stream>>>(srcv, dstv, E, rowptr, cnt, dinv, er);

    int gemmBlocks = (N + 127) / 128;
    int aggBlocks  = (N + 3) / 4;
    k_gemm1<<<gemmBlocks, 256, 0, stream>>>(x, whi1, wlo1, hA, N);
    k_agg<1, 1><<<aggBlocks, 256, 0, stream>>>(hA, rowptr, er, dinv, b1, hB, nullptr, N);
    k_gemm2<<<gemmBlocks, 256, 0, stream>>>(hB, whi2, wlo2, hA, N);
    k_agg<0, 0><<<aggBlocks, 256, 0, stream>>>(hA, rowptr, er, dinv, b2, nullptr, out, N);
}